// Round 16
// baseline (133.432 us; speedup 1.0000x reference)
//
#include <hip/hip_runtime.h>
#include <hip/hip_bf16.h>

#define BB 8
#define NN 512
#define DD 256
#define NROWS (BB*NN)   // 4096
#define JT 16           // attn j-tile

using bf16x8 = __attribute__((ext_vector_type(8))) short;
using f32x4  = __attribute__((ext_vector_type(4))) float;
typedef unsigned short us_t;

__device__ __forceinline__ us_t f2bf(float x) {
    union { float f; unsigned int u; } v; v.f = x;
    unsigned int r = (v.u + 0x7fffu + ((v.u >> 16) & 1u)) >> 16;
    return (us_t)r;
}

// ---- k1: [0,256) lin1 (f32 W1, XCD-pinned) | [256,320) W2 cvt + ctr zero |
//          [320,2368) pack (XCD-pinned) ----
__global__ __launch_bounds__(256) void k1(
    const float* __restrict__ w1f, const float* __restrict__ bias1,
    const float* __restrict__ node_emb, const int* __restrict__ head_nodes,
    const float* __restrict__ wvec1, const int* __restrict__ flagidx,
    const float* __restrict__ flag_emb,
    us_t* __restrict__ hT, float* __restrict__ a1, float* __restrict__ c1,
    const float* __restrict__ w2f, us_t* __restrict__ Wb2,
    const int* __restrict__ adj, const int* __restrict__ et,
    unsigned char* __restrict__ pk, int* __restrict__ ctr)
{
    __shared__ float redA[64], redC[64];
    const int blk = blockIdx.x, t = threadIdx.x;

    if (blk >= 320) {       // coalesced pack, batch pinned to XCD (blk&7)
        int pb = blk - 320;                       // [0,2048)
        int pbid = ((pb & 7) << 8) | (pb >> 3);   // bijective remap
        int g = (pbid*256 + t)*4;
        int4 av = *(const int4*)(adj + g);
        int4 ev = *(const int4*)(et + g);
        uchar4 u;
        u.x = (unsigned char)((ev.x&15)|(av.x<<4));
        u.y = (unsigned char)((ev.y&15)|(av.y<<4));
        u.z = (unsigned char)((ev.z&15)|(av.z<<4));
        u.w = (unsigned char)((ev.w&15)|(av.w<<4));
        *(uchar4*)(pk + g) = u;
        return;
    }
    if (blk >= 256) {       // W2 f32 -> bf16 + barrier-counter zeroing
        if (blk == 256 && t < BB) ctr[t] = 0;
        int i = (blk - 256)*1024 + t*4;
        float4 wv = *(const float4*)(w2f + i);
        ushort4 u;
        u.x = f2bf(wv.x); u.y = f2bf(wv.y); u.z = f2bf(wv.z); u.w = f2bf(wv.w);
        *(ushort4*)&Wb2[i] = u;
        return;
    }

    // lin1, batch pinned to XCD: bid = (blk&7)*32 + (blk>>3)
    const int bid = ((blk & 7) << 5) | (blk >> 3);
    const int wave = t >> 6, lane = t & 63;
    const int lrow = lane & 15, kg = lane >> 4;
    const int r0 = bid * 16;
    const int dw = wave * 64;

    const int arow = r0 + lrow;
    const int nid = head_nodes[arow];

    f32x4 acc[4];
    #pragma unroll
    for (int n = 0; n < 4; ++n) acc[n] = (f32x4){0.f, 0.f, 0.f, 0.f};

    const float4* xr = (const float4*)(node_emb + (size_t)nid * DD);
    #pragma unroll
    for (int ks = 0; ks < DD/32; ++ks) {
        float4 xa = xr[ks*8 + kg*2];
        float4 xb = xr[ks*8 + kg*2 + 1];
        bf16x8 af;
        af[0] = (short)f2bf(xa.x); af[1] = (short)f2bf(xa.y);
        af[2] = (short)f2bf(xa.z); af[3] = (short)f2bf(xa.w);
        af[4] = (short)f2bf(xb.x); af[5] = (short)f2bf(xb.y);
        af[6] = (short)f2bf(xb.z); af[7] = (short)f2bf(xb.w);
        #pragma unroll
        for (int n = 0; n < 4; ++n) {
            const float4* wr = (const float4*)(w1f + (size_t)(dw + n*16 + lrow)*DD
                                                + ks*32 + kg*8);
            float4 wa = wr[0], wb = wr[1];
            bf16x8 bfr;
            bfr[0] = (short)f2bf(wa.x); bfr[1] = (short)f2bf(wa.y);
            bfr[2] = (short)f2bf(wa.z); bfr[3] = (short)f2bf(wa.w);
            bfr[4] = (short)f2bf(wb.x); bfr[5] = (short)f2bf(wb.y);
            bfr[6] = (short)f2bf(wb.z); bfr[7] = (short)f2bf(wb.w);
            acc[n] = __builtin_amdgcn_mfma_f32_16x16x32_bf16(af, bfr, acc[n], 0, 0, 0);
        }
    }

    const int b  = r0 >> 9;
    const int i0 = (r0 & 511) + kg*4;
    float pa[4] = {0.f,0.f,0.f,0.f}, pc[4] = {0.f,0.f,0.f,0.f};
    #pragma unroll
    for (int n = 0; n < 4; ++n) {
        int d = dw + n*16 + lrow;
        float bv = bias1[d];
        float whd = wvec1[d], wtd = wvec1[256+d];
        ushort4 u;
        #pragma unroll
        for (int r = 0; r < 4; ++r) {
            float v = acc[n][r] + bv;
            ((us_t*)&u)[r] = f2bf(v);
            pa[r] += v * whd;
            pc[r] += v * wtd;
        }
        *(ushort4*)&hT[(size_t)b*DD*NN + (size_t)d*NN + i0] = u;
    }
    #pragma unroll
    for (int r = 0; r < 4; ++r) {
        #pragma unroll
        for (int m = 1; m < 16; m <<= 1) {
            pa[r] += __shfl_xor(pa[r], m);
            pc[r] += __shfl_xor(pc[r], m);
        }
    }
    if (lrow == 0) {
        #pragma unroll
        for (int r = 0; r < 4; ++r) {
            redA[wave*16 + kg*4 + r] = pa[r];
            redC[wave*16 + kg*4 + r] = pc[r];
        }
    }
    __syncthreads();
    if (t < 128) {
        const int m = t >> 3, sub = t & 7;
        const int fi = flagidx[r0 + m];
        float fa = 0.f, fc = 0.f;
        #pragma unroll
        for (int q = 0; q < 4; ++q) {
            int e = sub*4 + q;
            float fe = flag_emb[fi*32 + e];
            fa += fe * wvec1[512 + e];
            fc += fe * wvec1[544 + e];
        }
        #pragma unroll
        for (int mm = 1; mm < 8; mm <<= 1) {
            fa += __shfl_xor(fa, mm);
            fc += __shfl_xor(fc, mm);
        }
        if (sub == 0) {
            float sa = fa, sc = fc;
            #pragma unroll
            for (int wv = 0; wv < 4; ++wv) { sa += redA[wv*16 + m]; sc += redC[wv*16 + m]; }
            a1[r0 + m] = sa;
            c1[r0 + m] = sc;
        }
    }
}

// ---- merged attn: phase A = attn1+lin2, per-batch spin barrier, phase B = attn2 ----
struct AttnParams {
    const unsigned char* pk;
    const float *edge_emb;
    const float *w1, *b1, *a1, *c1;
    const us_t  *hT1;
    const us_t  *Wb2; const float *bias2;
    const float *w2;  const int *flagidx; const float *flag_emb;
    us_t *hT2; float *a2; float *c2;
    const float *b2;
    float *outf;
    int *ctr;
};

__global__ __launch_bounds__(512) void attn_fused(AttnParams P)
{
    __shared__ __align__(16) float p[NN][JT+1];           // 34.8 KB
    __shared__ __align__(16) us_t Pb[JT][NN+8];           // 16.6 KB
    __shared__ __align__(16) us_t Sg[16][DD+8];           // 8.25 KB (phase A only)
    __shared__ float as[NN];
    __shared__ float edot[16];
    __shared__ float cjs[JT];
    __shared__ float redw[8][16];
    __shared__ float mj[JT];
    __shared__ float invden[JT];
    __shared__ float redA[128], redC[128];

    const int t = threadIdx.x;
    const int b  = blockIdx.x & 7;            // batch -> XCD pinning
    const int j0 = (blockIdx.x >> 3) * JT;
    const int wave = t >> 6, lane = t & 63;
    const int lrow = lane & 15, kg = lane >> 4;

    // ================= PHASE A: attn layer 1 + fused lin2 =================
    {
        as[t] = P.a1[b*NN + t];
        if (t < 16) {
            float s = 0.f;
            for (int e2 = 0; e2 < 32; ++e2)
                s += P.edge_emb[t*32 + e2] * P.w1[576 + e2];
            edot[t] = s;
        } else if (t < 32) {
            cjs[t-16] = P.c1[b*NN + j0 + (t-16)];
        }
        const float bias = P.b1[0];
        __syncthreads();

        const unsigned char* pkb = P.pk + (size_t)b*NN*NN + j0;
        #pragma unroll
        for (int it = 0; it < 4; ++it) {
            int lid4 = (it*512 + t) * 4;
            int i = lid4 >> 4, jj = lid4 & 15;
            uchar4 u = *(const uchar4*)(pkb + (size_t)i*NN + jj);
            float base = as[i] + bias;
            unsigned char uv[4] = {u.x, u.y, u.z, u.w};
            #pragma unroll
            for (int q = 0; q < 4; ++q) {
                float l = base + cjs[jj+q] + edot[uv[q] & 15];
                l = (l > 0.f) ? l : 0.1f*l;
                p[i][jj+q] = (uv[q] >> 4) ? l : -1.0e30f;
            }
        }
        __syncthreads();

        const int j = t & 15, grp = t >> 4;
        float lv[16];
        #pragma unroll
        for (int s = 0; s < 16; ++s) lv[s] = p[grp + s*32][j];
        float m = lv[0];
        #pragma unroll
        for (int s = 1; s < 16; ++s) m = fmaxf(m, lv[s]);
        m = fmaxf(m, __shfl_xor(m, 16));
        m = fmaxf(m, __shfl_xor(m, 32));
        if (lane < 16) redw[wave][lane] = m;
        __syncthreads();
        if (t < 16) {
            float mm = redw[0][t];
            #pragma unroll
            for (int wv = 1; wv < 8; ++wv) mm = fmaxf(mm, redw[wv][t]);
            mj[t] = mm;
        }
        __syncthreads();
        const float mmax = mj[j];
        float ssum = 0.f;
        #pragma unroll
        for (int s = 0; s < 16; ++s) {
            float v = __expf(lv[s] - mmax);
            Pb[j][grp + s*32] = f2bf(v);
            ssum += v;
        }
        ssum += __shfl_xor(ssum, 16);
        ssum += __shfl_xor(ssum, 32);
        if (lane < 16) redw[wave][lane] = ssum;
        __syncthreads();
        if (t < 16) {
            float sm = redw[0][t];
            #pragma unroll
            for (int wv = 1; wv < 8; ++wv) sm += redw[wv][t];
            invden[t] = 1.f / sm;
        }
        __syncthreads();

        const int dw = wave * 32;
        f32x4 acc[2];
        acc[0] = (f32x4){0.f,0.f,0.f,0.f};
        acc[1] = (f32x4){0.f,0.f,0.f,0.f};

        const us_t* hTb = P.hT1 + (size_t)b*DD*NN;
        const us_t* hp[2];
        hp[0] = hTb + (size_t)(dw + lrow)*NN + kg*8;
        hp[1] = hTb + (size_t)(dw + 16 + lrow)*NN + kg*8;

        #pragma unroll 4
        for (int ks = 0; ks < NN/32; ++ks) {
            int k0 = ks*32;
            bf16x8 afr = *(const bf16x8*)&Pb[lrow][kg*8 + k0];
            #pragma unroll
            for (int n = 0; n < 2; ++n) {
                bf16x8 bfr = *(const bf16x8*)(hp[n] + k0);
                acc[n] = __builtin_amdgcn_mfma_f32_16x16x32_bf16(afr, bfr, acc[n], 0, 0, 0);
            }
        }

        float idr[4];
        #pragma unroll
        for (int r = 0; r < 4; ++r) idr[r] = invden[kg*4 + r];
        #pragma unroll
        for (int n = 0; n < 2; ++n) {
            #pragma unroll
            for (int r = 0; r < 4; ++r) {
                float v = 1.f/(1.f + __expf(-acc[n][r]*idr[r]));
                Sg[kg*4 + r][dw + n*16 + lrow] = f2bf(v);
            }
        }
        __syncthreads();

        f32x4 acc2[2];
        acc2[0] = (f32x4){0.f,0.f,0.f,0.f};
        acc2[1] = (f32x4){0.f,0.f,0.f,0.f};
        #pragma unroll
        for (int ks = 0; ks < DD/32; ++ks) {
            bf16x8 af2 = *(const bf16x8*)&Sg[lrow][ks*32 + kg*8];
            #pragma unroll
            for (int n = 0; n < 2; ++n) {
                bf16x8 bf2 = *(const bf16x8*)(P.Wb2 + (size_t)(dw + n*16 + lrow)*DD
                                               + ks*32 + kg*8);
                acc2[n] = __builtin_amdgcn_mfma_f32_16x16x32_bf16(af2, bf2, acc2[n], 0, 0, 0);
            }
        }

        const int r0 = b*NN + j0;
        const int i0 = j0 + kg*4;
        float pa[4] = {0.f,0.f,0.f,0.f}, pc[4] = {0.f,0.f,0.f,0.f};
        #pragma unroll
        for (int n = 0; n < 2; ++n) {
            int d = dw + n*16 + lrow;
            float bv = P.bias2[d];
            float whd = P.w2[d], wtd = P.w2[256+d];
            ushort4 u;
            #pragma unroll
            for (int r = 0; r < 4; ++r) {
                float v = acc2[n][r] + bv;
                ((us_t*)&u)[r] = f2bf(v);
                pa[r] += v * whd;
                pc[r] += v * wtd;
            }
            *(ushort4*)&P.hT2[(size_t)b*DD*NN + (size_t)d*NN + i0] = u;
        }
        #pragma unroll
        for (int r = 0; r < 4; ++r) {
            #pragma unroll
            for (int mk = 1; mk < 16; mk <<= 1) {
                pa[r] += __shfl_xor(pa[r], mk);
                pc[r] += __shfl_xor(pc[r], mk);
            }
        }
        if (lrow == 0) {
            #pragma unroll
            for (int r = 0; r < 4; ++r) {
                redA[wave*16 + kg*4 + r] = pa[r];
                redC[wave*16 + kg*4 + r] = pc[r];
            }
        }
        __syncthreads();
        if (t < 128) {
            const int mrow = t >> 3, sub = t & 7;
            const int fi = P.flagidx[r0 + mrow];
            float fa = 0.f, fc = 0.f;
            #pragma unroll
            for (int q = 0; q < 4; ++q) {
                int e = sub*4 + q;
                float fe = P.flag_emb[fi*32 + e];
                fa += fe * P.w2[512 + e];
                fc += fe * P.w2[544 + e];
            }
            #pragma unroll
            for (int mm = 1; mm < 8; mm <<= 1) {
                fa += __shfl_xor(fa, mm);
                fc += __shfl_xor(fc, mm);
            }
            if (sub == 0) {
                float sa = fa, sc = fc;
                #pragma unroll
                for (int wv = 0; wv < 8; ++wv) { sa += redA[wv*16 + mrow]; sc += redC[wv*16 + mrow]; }
                P.a2[r0 + mrow] = sa;
                P.c2[r0 + mrow] = sc;
            }
        }
    }

    // ================= per-batch barrier (32 blocks of batch b) =================
    __syncthreads();
    __threadfence();
    __syncthreads();
    if (t == 0) {
        atomicAdd(P.ctr + b, 1);
        while (__hip_atomic_load(P.ctr + b, __ATOMIC_ACQUIRE,
                                 __HIP_MEMORY_SCOPE_AGENT) < 32) {}
    }
    __syncthreads();
    __threadfence();

    // ================= PHASE B: attn layer 2 -> d_out =================
    {
        as[t] = P.a2[b*NN + t];
        if (t < 16) {
            float s = 0.f;
            for (int e2 = 0; e2 < 32; ++e2)
                s += P.edge_emb[t*32 + e2] * P.w2[576 + e2];
            edot[t] = s;
        } else if (t < 32) {
            cjs[t-16] = P.c2[b*NN + j0 + (t-16)];
        }
        const float bias = P.b2[0];
        __syncthreads();

        const unsigned char* pkb = P.pk + (size_t)b*NN*NN + j0;
        #pragma unroll
        for (int it = 0; it < 4; ++it) {
            int lid4 = (it*512 + t) * 4;
            int i = lid4 >> 4, jj = lid4 & 15;
            uchar4 u = *(const uchar4*)(pkb + (size_t)i*NN + jj);
            float base = as[i] + bias;
            unsigned char uv[4] = {u.x, u.y, u.z, u.w};
            #pragma unroll
            for (int q = 0; q < 4; ++q) {
                float l = base + cjs[jj+q] + edot[uv[q] & 15];
                l = (l > 0.f) ? l : 0.1f*l;
                p[i][jj+q] = (uv[q] >> 4) ? l : -1.0e30f;
            }
        }
        __syncthreads();

        const int j = t & 15, grp = t >> 4;
        float lv[16];
        #pragma unroll
        for (int s = 0; s < 16; ++s) lv[s] = p[grp + s*32][j];
        float m = lv[0];
        #pragma unroll
        for (int s = 1; s < 16; ++s) m = fmaxf(m, lv[s]);
        m = fmaxf(m, __shfl_xor(m, 16));
        m = fmaxf(m, __shfl_xor(m, 32));
        if (lane < 16) redw[wave][lane] = m;
        __syncthreads();
        if (t < 16) {
            float mm = redw[0][t];
            #pragma unroll
            for (int wv = 1; wv < 8; ++wv) mm = fmaxf(mm, redw[wv][t]);
            mj[t] = mm;
        }
        __syncthreads();
        const float mmax = mj[j];
        float ssum = 0.f;
        #pragma unroll
        for (int s = 0; s < 16; ++s) {
            float v = __expf(lv[s] - mmax);
            Pb[j][grp + s*32] = f2bf(v);
            ssum += v;
        }
        ssum += __shfl_xor(ssum, 16);
        ssum += __shfl_xor(ssum, 32);
        if (lane < 16) redw[wave][lane] = ssum;
        __syncthreads();
        if (t < 16) {
            float sm = redw[0][t];
            #pragma unroll
            for (int wv = 1; wv < 8; ++wv) sm += redw[wv][t];
            invden[t] = 1.f / sm;
        }
        __syncthreads();

        const int dw = wave * 32;
        f32x4 acc[2];
        acc[0] = (f32x4){0.f,0.f,0.f,0.f};
        acc[1] = (f32x4){0.f,0.f,0.f,0.f};

        const us_t* hTb = P.hT2 + (size_t)b*DD*NN;
        const us_t* hp[2];
        hp[0] = hTb + (size_t)(dw + lrow)*NN + kg*8;
        hp[1] = hTb + (size_t)(dw + 16 + lrow)*NN + kg*8;

        #pragma unroll 4
        for (int ks = 0; ks < NN/32; ++ks) {
            int k0 = ks*32;
            bf16x8 afr = *(const bf16x8*)&Pb[lrow][kg*8 + k0];
            #pragma unroll
            for (int n = 0; n < 2; ++n) {
                bf16x8 bfr = *(const bf16x8*)(hp[n] + k0);
                acc[n] = __builtin_amdgcn_mfma_f32_16x16x32_bf16(afr, bfr, acc[n], 0, 0, 0);
            }
        }

        float idr[4];
        #pragma unroll
        for (int r = 0; r < 4; ++r) idr[r] = invden[kg*4 + r];
        #pragma unroll
        for (int n = 0; n < 2; ++n) {
            #pragma unroll
            for (int r = 0; r < 4; ++r) {
                int jj = j0 + kg*4 + r;
                int dd = dw + n*16 + lrow;
                P.outf[(size_t)(b*NN + jj)*DD + dd] = acc[n][r] * idr[r];
            }
        }
    }
}

extern "C" void kernel_launch(void* const* d_in, const int* in_sizes, int n_in,
                              void* d_out, int out_size, void* d_ws, size_t ws_size,
                              hipStream_t stream) {
    (void)in_sizes; (void)n_in; (void)out_size; (void)ws_size;
    const int*   adj       = (const int*)d_in[0];
    const int*   head_nodes= (const int*)d_in[1];
    const int*   head_flag = (const int*)d_in[2];
    const int*   etype     = (const int*)d_in[3];
    const float* node_emb  = (const float*)d_in[4];
    const float* edge_emb  = (const float*)d_in[5];
    const float* flag_emb  = (const float*)d_in[6];
    const float* t1_w      = (const float*)d_in[7];
    const float* t1_b      = (const float*)d_in[8];
    const float* w1        = (const float*)d_in[9];
    const float* b1        = (const float*)d_in[10];
    const float* t2_w      = (const float*)d_in[11];
    const float* t2_b      = (const float*)d_in[12];
    const float* w2        = (const float*)d_in[13];
    const float* b2        = (const float*)d_in[14];

    us_t* hT1 = (us_t*)d_ws;                         // 2 MB bf16 [b][d][i]
    us_t* hT2 = hT1 + (size_t)NROWS*DD;              // 2 MB
    us_t* Wb2 = hT2 + (size_t)NROWS*DD;              // 128 KB
    unsigned char* pk = (unsigned char*)(Wb2 + (size_t)DD*DD);  // 2 MB
    float* a1 = (float*)(pk + (size_t)BB*NN*NN);
    float* c1 = a1 + NROWS;
    float* a2 = c1 + NROWS;
    float* c2 = a2 + NROWS;
    int*   ctr = (int*)(c2 + NROWS);                 // 8 ints

    k1<<<320 + BB*NN*NN/1024, 256, 0, stream>>>(
        t1_w, t1_b, node_emb, head_nodes, w1, head_flag, flag_emb,
        hT1, a1, c1, t2_w, Wb2, adj, etype, pk, ctr);

    AttnParams P;
    P.pk = pk; P.edge_emb = edge_emb;
    P.w1 = w1; P.b1 = b1; P.a1 = a1; P.c1 = c1;
    P.hT1 = hT1;
    P.Wb2 = Wb2; P.bias2 = t2_b;
    P.w2 = w2; P.flagidx = head_flag; P.flag_emb = flag_emb;
    P.hT2 = hT2; P.a2 = a2; P.c2 = c2;
    P.b2 = b2;
    P.outf = (float*)d_out;
    P.ctr = ctr;

    void* args[] = { &P };
    hipLaunchCooperativeKernel((const void*)attn_fused, dim3(BB*(NN/JT)),
                               dim3(512), args, 0, stream);
}

// Round 17
// 46.153 us; speedup vs baseline: 2.8911x; 2.8911x over previous
//
#include <hip/hip_runtime.h>
#include <hip/hip_bf16.h>

#define BB 8
#define NN 512
#define DD 256
#define NROWS (BB*NN)   // 4096
#define JT 16           // attn j-tile

using bf16x8 = __attribute__((ext_vector_type(8))) short;
using f32x4  = __attribute__((ext_vector_type(4))) float;
typedef unsigned short us_t;

__device__ __forceinline__ us_t f2bf(float x) {
    union { float f; unsigned int u; } v; v.f = x;
    unsigned int r = (v.u + 0x7fffu + ((v.u >> 16) & 1u)) >> 16;
    return (us_t)r;
}

// ---- k1: [0,256) lin1 (f32 W1, XCD-pinned) | [256,320) W2 cvt |
//          [320,2368) pack (XCD-pinned) ----  (round-15 verbatim)
__global__ __launch_bounds__(256) void k1(
    const float* __restrict__ w1f, const float* __restrict__ bias1,
    const float* __restrict__ node_emb, const int* __restrict__ head_nodes,
    const float* __restrict__ wvec1, const int* __restrict__ flagidx,
    const float* __restrict__ flag_emb,
    us_t* __restrict__ hT, float* __restrict__ a1, float* __restrict__ c1,
    const float* __restrict__ w2f, us_t* __restrict__ Wb2,
    const int* __restrict__ adj, const int* __restrict__ et,
    unsigned char* __restrict__ pk)
{
    __shared__ float redA[64], redC[64];
    const int blk = blockIdx.x, t = threadIdx.x;

    if (blk >= 320) {       // coalesced pack, batch pinned to XCD (blk&7)
        int pb = blk - 320;                       // [0,2048)
        int pbid = ((pb & 7) << 8) | (pb >> 3);   // bijective remap
        int g = (pbid*256 + t)*4;
        int4 av = *(const int4*)(adj + g);
        int4 ev = *(const int4*)(et + g);
        uchar4 u;
        u.x = (unsigned char)((ev.x&15)|(av.x<<4));
        u.y = (unsigned char)((ev.y&15)|(av.y<<4));
        u.z = (unsigned char)((ev.z&15)|(av.z<<4));
        u.w = (unsigned char)((ev.w&15)|(av.w<<4));
        *(uchar4*)(pk + g) = u;
        return;
    }
    if (blk >= 256) {       // W2 f32 -> bf16 (consumed next dispatch)
        int i = (blk - 256)*1024 + t*4;
        float4 wv = *(const float4*)(w2f + i);
        ushort4 u;
        u.x = f2bf(wv.x); u.y = f2bf(wv.y); u.z = f2bf(wv.z); u.w = f2bf(wv.w);
        *(ushort4*)&Wb2[i] = u;
        return;
    }

    // lin1, batch pinned to XCD: bid = (blk&7)*32 + (blk>>3)
    const int bid = ((blk & 7) << 5) | (blk >> 3);
    const int wave = t >> 6, lane = t & 63;
    const int lrow = lane & 15, kg = lane >> 4;
    const int r0 = bid * 16;
    const int dw = wave * 64;

    const int arow = r0 + lrow;
    const int nid = head_nodes[arow];

    f32x4 acc[4];
    #pragma unroll
    for (int n = 0; n < 4; ++n) acc[n] = (f32x4){0.f, 0.f, 0.f, 0.f};

    const float4* xr = (const float4*)(node_emb + (size_t)nid * DD);
    #pragma unroll
    for (int ks = 0; ks < DD/32; ++ks) {
        float4 xa = xr[ks*8 + kg*2];
        float4 xb = xr[ks*8 + kg*2 + 1];
        bf16x8 af;
        af[0] = (short)f2bf(xa.x); af[1] = (short)f2bf(xa.y);
        af[2] = (short)f2bf(xa.z); af[3] = (short)f2bf(xa.w);
        af[4] = (short)f2bf(xb.x); af[5] = (short)f2bf(xb.y);
        af[6] = (short)f2bf(xb.z); af[7] = (short)f2bf(xb.w);
        #pragma unroll
        for (int n = 0; n < 4; ++n) {
            const float4* wr = (const float4*)(w1f + (size_t)(dw + n*16 + lrow)*DD
                                                + ks*32 + kg*8);
            float4 wa = wr[0], wb = wr[1];
            bf16x8 bfr;
            bfr[0] = (short)f2bf(wa.x); bfr[1] = (short)f2bf(wa.y);
            bfr[2] = (short)f2bf(wa.z); bfr[3] = (short)f2bf(wa.w);
            bfr[4] = (short)f2bf(wb.x); bfr[5] = (short)f2bf(wb.y);
            bfr[6] = (short)f2bf(wb.z); bfr[7] = (short)f2bf(wb.w);
            acc[n] = __builtin_amdgcn_mfma_f32_16x16x32_bf16(af, bfr, acc[n], 0, 0, 0);
        }
    }

    const int b  = r0 >> 9;
    const int i0 = (r0 & 511) + kg*4;
    float pa[4] = {0.f,0.f,0.f,0.f}, pc[4] = {0.f,0.f,0.f,0.f};
    #pragma unroll
    for (int n = 0; n < 4; ++n) {
        int d = dw + n*16 + lrow;
        float bv = bias1[d];
        float whd = wvec1[d], wtd = wvec1[256+d];
        ushort4 u;
        #pragma unroll
        for (int r = 0; r < 4; ++r) {
            float v = acc[n][r] + bv;
            ((us_t*)&u)[r] = f2bf(v);
            pa[r] += v * whd;
            pc[r] += v * wtd;
        }
        *(ushort4*)&hT[(size_t)b*DD*NN + (size_t)d*NN + i0] = u;
    }
    #pragma unroll
    for (int r = 0; r < 4; ++r) {
        #pragma unroll
        for (int m = 1; m < 16; m <<= 1) {
            pa[r] += __shfl_xor(pa[r], m);
            pc[r] += __shfl_xor(pc[r], m);
        }
    }
    if (lrow == 0) {
        #pragma unroll
        for (int r = 0; r < 4; ++r) {
            redA[wave*16 + kg*4 + r] = pa[r];
            redC[wave*16 + kg*4 + r] = pc[r];
        }
    }
    __syncthreads();
    if (t < 128) {
        const int m = t >> 3, sub = t & 7;
        const int fi = flagidx[r0 + m];
        float fa = 0.f, fc = 0.f;
        #pragma unroll
        for (int q = 0; q < 4; ++q) {
            int e = sub*4 + q;
            float fe = flag_emb[fi*32 + e];
            fa += fe * wvec1[512 + e];
            fc += fe * wvec1[544 + e];
        }
        #pragma unroll
        for (int mm = 1; mm < 8; mm <<= 1) {
            fa += __shfl_xor(fa, mm);
            fc += __shfl_xor(fc, mm);
        }
        if (sub == 0) {
            float sa = fa, sc = fc;
            #pragma unroll
            for (int wv = 0; wv < 4; ++wv) { sa += redA[wv*16 + m]; sc += redC[wv*16 + m]; }
            a1[r0 + m] = sa;
            c1[r0 + m] = sc;
        }
    }
}

// ---- k2: attn layer 1 + fused lin2; byte-LDS logit staging ----
__global__ __launch_bounds__(512) void attn1_lin2(
    const unsigned char* __restrict__ pk,
    const float* __restrict__ edge_emb, const float* __restrict__ w,
    const float* __restrict__ bptr,
    const float* __restrict__ a, const float* __restrict__ c,
    const us_t* __restrict__ hT,
    const us_t* __restrict__ Wb2, const float* __restrict__ bias2,
    const float* __restrict__ wvec2, const int* __restrict__ flagidx,
    const float* __restrict__ flag_emb,
    us_t* __restrict__ hT2, float* __restrict__ a2, float* __restrict__ c2)
{
    __shared__ __align__(16) unsigned char pkl[NN][JT];   // 8 KB raw bytes
    __shared__ __align__(16) us_t Pb[JT][NN+8];           // 16.6 KB (unnormalized exp)
    __shared__ __align__(16) us_t Sg[16][DD+8];           // 8.25 KB
    __shared__ float as[NN];
    __shared__ float edot[16];
    __shared__ float cjs[JT];
    __shared__ float redw[8][16];
    __shared__ float mj[JT];
    __shared__ float invden[JT];
    __shared__ float redA[128], redC[128];

    const int t = threadIdx.x;
    const int b  = blockIdx.x & 7;            // batch -> XCD pinning
    const int j0 = (blockIdx.x >> 3) * JT;
    const int wave = t >> 6, lane = t & 63;

    as[t] = a[b*NN + t];
    if (t < 16) {
        float s = 0.f;
        for (int e2 = 0; e2 < 32; ++e2)
            s += edge_emb[t*32 + e2] * w[576 + e2];
        edot[t] = s;
    } else if (t < 32) {
        cjs[t-16] = c[b*NN + j0 + (t-16)];
    }
    const float bias = bptr[0];
    __syncthreads();

    // ---- stage raw packed bytes to LDS (coalesced uchar4, no compute) ----
    const unsigned char* pkb = pk + (size_t)b*NN*NN + j0;
    #pragma unroll
    for (int it = 0; it < 4; ++it) {
        int lid4 = (it*512 + t) * 4;
        int i = lid4 >> 4, jj = lid4 & 15;
        *(uchar4*)&pkl[i][jj] = *(const uchar4*)(pkb + (size_t)i*NN + jj);
    }
    __syncthreads();

    // ---- single-pass softmax: logits computed in regs from bytes ----
    const int j = t & 15, grp = t >> 4;    // grp 0..31
    const float cjb = cjs[j] + bias;
    float lv[16];
    #pragma unroll
    for (int s = 0; s < 16; ++s) {
        int i = grp + s*32;
        unsigned char by = pkl[i][j];
        float l = as[i] + cjb + edot[by & 15];
        l = (l > 0.f) ? l : 0.1f*l;
        lv[s] = (by >> 4) ? l : -1.0e30f;
    }
    float m = lv[0];
    #pragma unroll
    for (int s = 1; s < 16; ++s) m = fmaxf(m, lv[s]);
    m = fmaxf(m, __shfl_xor(m, 16));
    m = fmaxf(m, __shfl_xor(m, 32));
    if (lane < 16) redw[wave][lane] = m;
    __syncthreads();
    if (t < 16) {
        float mm = redw[0][t];
        #pragma unroll
        for (int wv = 1; wv < 8; ++wv) mm = fmaxf(mm, redw[wv][t]);
        mj[t] = mm;
    }
    __syncthreads();
    const float mmax = mj[j];
    float ssum = 0.f;
    #pragma unroll
    for (int s = 0; s < 16; ++s) {
        float v = __expf(lv[s] - mmax);
        Pb[j][grp + s*32] = f2bf(v);
        ssum += v;
    }
    ssum += __shfl_xor(ssum, 16);
    ssum += __shfl_xor(ssum, 32);
    if (lane < 16) redw[wave][lane] = ssum;
    __syncthreads();
    if (t < 16) {
        float sm = redw[0][t];
        #pragma unroll
        for (int wv = 1; wv < 8; ++wv) sm += redw[wv][t];
        invden[t] = 1.f / sm;
    }
    __syncthreads();

    // ---- MFMA1: out[16 j][256 d]; 8 waves, wave -> d slice of 32 ----
    const int dw = wave * 32;
    const int lrow = lane & 15;
    const int kg   = lane >> 4;
    f32x4 acc[2];
    acc[0] = (f32x4){0.f,0.f,0.f,0.f};
    acc[1] = (f32x4){0.f,0.f,0.f,0.f};

    const us_t* hTb = hT + (size_t)b*DD*NN;
    const us_t* hp[2];
    hp[0] = hTb + (size_t)(dw + lrow)*NN + kg*8;
    hp[1] = hTb + (size_t)(dw + 16 + lrow)*NN + kg*8;

    #pragma unroll 4
    for (int ks = 0; ks < NN/32; ++ks) {
        int k0 = ks*32;
        bf16x8 afr = *(const bf16x8*)&Pb[lrow][kg*8 + k0];
        #pragma unroll
        for (int n = 0; n < 2; ++n) {
            bf16x8 bfr = *(const bf16x8*)(hp[n] + k0);
            acc[n] = __builtin_amdgcn_mfma_f32_16x16x32_bf16(afr, bfr, acc[n], 0, 0, 0);
        }
    }

    // normalize rows by invden (C/D row = kg*4+r) then sigmoid -> Sg
    float idr[4];
    #pragma unroll
    for (int r = 0; r < 4; ++r) idr[r] = invden[kg*4 + r];
    #pragma unroll
    for (int n = 0; n < 2; ++n) {
        #pragma unroll
        for (int r = 0; r < 4; ++r) {
            float v = 1.f/(1.f + __expf(-acc[n][r]*idr[r]));
            Sg[kg*4 + r][dw + n*16 + lrow] = f2bf(v);
        }
    }
    __syncthreads();

    // ---- MFMA2 (lin2): h2[16 rows][256 d2] = Sg (16x256) x W2^T ----
    f32x4 acc2[2];
    acc2[0] = (f32x4){0.f,0.f,0.f,0.f};
    acc2[1] = (f32x4){0.f,0.f,0.f,0.f};
    #pragma unroll
    for (int ks = 0; ks < DD/32; ++ks) {
        bf16x8 af2 = *(const bf16x8*)&Sg[lrow][ks*32 + kg*8];
        #pragma unroll
        for (int n = 0; n < 2; ++n) {
            bf16x8 bf2 = *(const bf16x8*)(Wb2 + (size_t)(dw + n*16 + lrow)*DD
                                           + ks*32 + kg*8);
            acc2[n] = __builtin_amdgcn_mfma_f32_16x16x32_bf16(af2, bf2, acc2[n], 0, 0, 0);
        }
    }

    // ---- lin2 epilogue: hT2 + a2/c2 ----
    const int r0 = b*NN + j0;
    const int i0 = j0 + kg*4;
    float pa[4] = {0.f,0.f,0.f,0.f}, pc[4] = {0.f,0.f,0.f,0.f};
    #pragma unroll
    for (int n = 0; n < 2; ++n) {
        int d = dw + n*16 + lrow;
        float bv = bias2[d];
        float whd = wvec2[d], wtd = wvec2[256+d];
        ushort4 u;
        #pragma unroll
        for (int r = 0; r < 4; ++r) {
            float v = acc2[n][r] + bv;
            ((us_t*)&u)[r] = f2bf(v);
            pa[r] += v * whd;
            pc[r] += v * wtd;
        }
        *(ushort4*)&hT2[(size_t)b*DD*NN + (size_t)d*NN + i0] = u;
    }
    #pragma unroll
    for (int r = 0; r < 4; ++r) {
        #pragma unroll
        for (int mk = 1; mk < 16; mk <<= 1) {
            pa[r] += __shfl_xor(pa[r], mk);
            pc[r] += __shfl_xor(pc[r], mk);
        }
    }
    if (lrow == 0) {
        #pragma unroll
        for (int r = 0; r < 4; ++r) {
            redA[wave*16 + kg*4 + r] = pa[r];
            redC[wave*16 + kg*4 + r] = pc[r];
        }
    }
    __syncthreads();
    if (t < 128) {
        const int mrow = t >> 3, sub = t & 7;      // mrow 0..15
        const int fi = flagidx[r0 + mrow];
        float fa = 0.f, fc = 0.f;
        #pragma unroll
        for (int q = 0; q < 4; ++q) {
            int e = sub*4 + q;
            float fe = flag_emb[fi*32 + e];
            fa += fe * wvec2[512 + e];
            fc += fe * wvec2[544 + e];
        }
        #pragma unroll
        for (int mm = 1; mm < 8; mm <<= 1) {
            fa += __shfl_xor(fa, mm);
            fc += __shfl_xor(fc, mm);
        }
        if (sub == 0) {
            float sa = fa, sc = fc;
            #pragma unroll
            for (int wv = 0; wv < 8; ++wv) { sa += redA[wv*16 + mrow]; sc += redC[wv*16 + mrow]; }
            a2[r0 + mrow] = sa;
            c2[r0 + mrow] = sc;
        }
    }
}

// ---- k3: attn layer 2; byte-LDS logit staging; writes f32 d_out ----
__global__ __launch_bounds__(512) void attn2(
    const unsigned char* __restrict__ pk,
    const float* __restrict__ edge_emb, const float* __restrict__ w,
    const float* __restrict__ bptr,
    const float* __restrict__ a, const float* __restrict__ c,
    const us_t* __restrict__ hT,
    float* __restrict__ outf)
{
    __shared__ __align__(16) unsigned char pkl[NN][JT];
    __shared__ __align__(16) us_t Pb[JT][NN+8];
    __shared__ float as[NN];
    __shared__ float edot[16];
    __shared__ float cjs[JT];
    __shared__ float redw[8][16];
    __shared__ float mj[JT];
    __shared__ float invden[JT];

    const int t = threadIdx.x;
    const int b  = blockIdx.x & 7;            // batch -> XCD pinning
    const int j0 = (blockIdx.x >> 3) * JT;
    const int wave = t >> 6, lane = t & 63;

    as[t] = a[b*NN + t];
    if (t < 16) {
        float s = 0.f;
        for (int e2 = 0; e2 < 32; ++e2)
            s += edge_emb[t*32 + e2] * w[576 + e2];
        edot[t] = s;
    } else if (t < 32) {
        cjs[t-16] = c[b*NN + j0 + (t-16)];
    }
    const float bias = bptr[0];
    __syncthreads();

    const unsigned char* pkb = pk + (size_t)b*NN*NN + j0;
    #pragma unroll
    for (int it = 0; it < 4; ++it) {
        int lid4 = (it*512 + t) * 4;
        int i = lid4 >> 4, jj = lid4 & 15;
        *(uchar4*)&pkl[i][jj] = *(const uchar4*)(pkb + (size_t)i*NN + jj);
    }
    __syncthreads();

    const int j = t & 15, grp = t >> 4;
    const float cjb = cjs[j] + bias;
    float lv[16];
    #pragma unroll
    for (int s = 0; s < 16; ++s) {
        int i = grp + s*32;
        unsigned char by = pkl[i][j];
        float l = as[i] + cjb + edot[by & 15];
        l = (l > 0.f) ? l : 0.1f*l;
        lv[s] = (by >> 4) ? l : -1.0e30f;
    }
    float m = lv[0];
    #pragma unroll
    for (int s = 1; s < 16; ++s) m = fmaxf(m, lv[s]);
    m = fmaxf(m, __shfl_xor(m, 16));
    m = fmaxf(m, __shfl_xor(m, 32));
    if (lane < 16) redw[wave][lane] = m;
    __syncthreads();
    if (t < 16) {
        float mm = redw[0][t];
        #pragma unroll
        for (int wv = 1; wv < 8; ++wv) mm = fmaxf(mm, redw[wv][t]);
        mj[t] = mm;
    }
    __syncthreads();
    const float mmax = mj[j];
    float ssum = 0.f;
    #pragma unroll
    for (int s = 0; s < 16; ++s) {
        float v = __expf(lv[s] - mmax);
        Pb[j][grp + s*32] = f2bf(v);
        ssum += v;
    }
    ssum += __shfl_xor(ssum, 16);
    ssum += __shfl_xor(ssum, 32);
    if (lane < 16) redw[wave][lane] = ssum;
    __syncthreads();
    if (t < 16) {
        float sm = redw[0][t];
        #pragma unroll
        for (int wv = 1; wv < 8; ++wv) sm += redw[wv][t];
        invden[t] = 1.f / sm;
    }
    __syncthreads();

    const int dw = wave * 32;
    const int lrow = lane & 15;
    const int kg   = lane >> 4;
    f32x4 acc[2];
    acc[0] = (f32x4){0.f,0.f,0.f,0.f};
    acc[1] = (f32x4){0.f,0.f,0.f,0.f};

    const us_t* hTb = hT + (size_t)b*DD*NN;
    const us_t* hp[2];
    hp[0] = hTb + (size_t)(dw + lrow)*NN + kg*8;
    hp[1] = hTb + (size_t)(dw + 16 + lrow)*NN + kg*8;

    #pragma unroll 4
    for (int ks = 0; ks < NN/32; ++ks) {
        int k0 = ks*32;
        bf16x8 afr = *(const bf16x8*)&Pb[lrow][kg*8 + k0];
        #pragma unroll
        for (int n = 0; n < 2; ++n) {
            bf16x8 bfr = *(const bf16x8*)(hp[n] + k0);
            acc[n] = __builtin_amdgcn_mfma_f32_16x16x32_bf16(afr, bfr, acc[n], 0, 0, 0);
        }
    }

    float idr[4];
    #pragma unroll
    for (int r = 0; r < 4; ++r) idr[r] = invden[kg*4 + r];
    #pragma unroll
    for (int n = 0; n < 2; ++n) {
        #pragma unroll
        for (int r = 0; r < 4; ++r) {
            int jj = j0 + kg*4 + r;
            int dd = dw + n*16 + lrow;
            outf[(size_t)(b*NN + jj)*DD + dd] = acc[n][r] * idr[r];
        }
    }
}

extern "C" void kernel_launch(void* const* d_in, const int* in_sizes, int n_in,
                              void* d_out, int out_size, void* d_ws, size_t ws_size,
                              hipStream_t stream) {
    (void)in_sizes; (void)n_in; (void)out_size; (void)ws_size;
    const int*   adj       = (const int*)d_in[0];
    const int*   head_nodes= (const int*)d_in[1];
    const int*   head_flag = (const int*)d_in[2];
    const int*   etype     = (const int*)d_in[3];
    const float* node_emb  = (const float*)d_in[4];
    const float* edge_emb  = (const float*)d_in[5];
    const float* flag_emb  = (const float*)d_in[6];
    const float* t1_w      = (const float*)d_in[7];
    const float* t1_b      = (const float*)d_in[8];
    const float* w1        = (const float*)d_in[9];
    const float* b1        = (const float*)d_in[10];
    const float* t2_w      = (const float*)d_in[11];
    const float* t2_b      = (const float*)d_in[12];
    const float* w2        = (const float*)d_in[13];
    const float* b2        = (const float*)d_in[14];

    us_t* hT1 = (us_t*)d_ws;                         // 2 MB bf16 [b][d][i]
    us_t* hT2 = hT1 + (size_t)NROWS*DD;              // 2 MB
    us_t* Wb2 = hT2 + (size_t)NROWS*DD;              // 128 KB
    unsigned char* pk = (unsigned char*)(Wb2 + (size_t)DD*DD);  // 2 MB
    float* a1 = (float*)(pk + (size_t)BB*NN*NN);
    float* c1 = a1 + NROWS;
    float* a2 = c1 + NROWS;
    float* c2 = a2 + NROWS;

    k1<<<320 + BB*NN*NN/1024, 256, 0, stream>>>(
        t1_w, t1_b, node_emb, head_nodes, w1, head_flag, flag_emb,
        hT1, a1, c1, t2_w, Wb2, adj, etype, pk);
    attn1_lin2<<<BB*(NN/JT), 512, 0, stream>>>(
        pk, edge_emb, w1, b1, a1, c1, hT1,
        Wb2, t2_b, w2, head_flag, flag_emb, hT2, a2, c2);
    attn2<<<BB*(NN/JT), 512, 0, stream>>>(
        pk, edge_emb, w2, b2, a2, c2, hT2, (float*)d_out);
}